// Round 3
// baseline (32.791 us; speedup 1.0000x reference)
//
#include <hip/hip_runtime.h>
#include <hip/hip_bf16.h>

// RCNN bbox target generator: elementwise over N boxes. Memory-bound.
// Traffic: 88MB reads + 96MB writes = 184MB -> 29.3us floor at 6.29TB/s copy BW.
//
// R2: 512-box tiles, 2 boxes/thread. Raises memory-level parallelism
// (~5 outstanding float4 staging loads/thread + 2 label loads issued before
// the barrier) and halves block count. All global accesses are float4 or
// 4B coalesced; LDS reads are stride-5 (2 lanes/bank = free per m136).
//
// Output d_out (f32, 12N floats):
//   [0,4N) bbox_targets | [4N,8N) inside_weights | [8N,12N) outside_weights

#define BLOCK 256
#define TILE  512   // boxes per block (2 per thread)

__global__ __launch_bounds__(BLOCK) void rcnn_target_kernel(
    const float* __restrict__ gt_rois,
    const float* __restrict__ rois,
    const int*   __restrict__ labels,
    const float* __restrict__ means,
    const float* __restrict__ stds,
    const float* __restrict__ inside_w,
    float* __restrict__ out,
    int n)
{
    __shared__ float sg[TILE * 5];   // 10240 B
    __shared__ float sr[TILE * 5];   // 10240 B

    const int t    = threadIdx.x;
    const int base = blockIdx.x * TILE;
    const int rem  = min(TILE, n - base);        // boxes in this tile
    const int nflt = 5 * rem;
    const int nvec = nflt >> 2;                  // whole float4s to stage

    const int i0 = base + t;
    const int i1 = base + BLOCK + t;

    // Issue label loads early so they overlap the staging loads.
    int lab0 = (t < rem)          ? labels[i0] : 0;
    int lab1 = (BLOCK + t < rem)  ? labels[i1] : 0;

    const float4* __restrict__ g4 = reinterpret_cast<const float4*>(gt_rois + (size_t)base * 5);
    const float4* __restrict__ r4 = reinterpret_cast<const float4*>(rois    + (size_t)base * 5);
    float4* __restrict__ sg4 = reinterpret_cast<float4*>(sg);
    float4* __restrict__ sr4 = reinterpret_cast<float4*>(sr);

    for (int idx = t; idx < nvec; idx += BLOCK) {
        sg4[idx] = g4[idx];
        sr4[idx] = r4[idx];
    }
    if (t == 0) {                                // scalar tail (partial last tile only)
        for (int f = nvec * 4; f < nflt; ++f) {
            sg[f] = gt_rois[(size_t)base * 5 + f];
            sr[f] = rois[(size_t)base * 5 + f];
        }
    }
    __syncthreads();

    // Parameter vectors: broadcast scalar loads, L1-resident.
    const float m0 = means[0], m1 = means[1], m2 = means[2], m3 = means[3];
    const float rs0 = 1.0f / stds[0], rs1 = 1.0f / stds[1];
    const float rs2 = 1.0f / stds[2], rs3 = 1.0f / stds[3];
    const float iw0 = inside_w[0], iw1 = inside_w[1];
    const float iw2 = inside_w[2], iw3 = inside_w[3];

    float4* __restrict__ out_t  = reinterpret_cast<float4*>(out);
    float4* __restrict__ out_wi = reinterpret_cast<float4*>(out + 4ull * (size_t)n);
    float4* __restrict__ out_wo = reinterpret_cast<float4*>(out + 8ull * (size_t)n);

    #pragma unroll
    for (int k = 0; k < 2; ++k) {
        const int lt = k * BLOCK + t;            // index within tile
        const int i  = base + lt;                // global box index
        if (i >= n) break;
        const int lab = (k == 0) ? lab0 : lab1;

        const float* g = sg + 5 * lt;            // gt box: record cols 0:4
        const float* r = sr + 5 * lt + 1;        // ex box: record cols 1:5

        const float gx1 = g[0], gy1 = g[1], gx2 = g[2], gy2 = g[3];
        const float ex1 = r[0], ey1 = r[1], ex2 = r[2], ey2 = r[3];

        const float ew  = ex2 - ex1 + 1.0f;
        const float eh  = ey2 - ey1 + 1.0f;
        const float ecx = ex1 + 0.5f * ew;
        const float ecy = ey1 + 0.5f * eh;
        const float gw  = gx2 - gx1 + 1.0f;
        const float gh  = gy2 - gy1 + 1.0f;
        const float gcx = gx1 + 0.5f * gw;
        const float gcy = gy1 + 0.5f * gh;

        const float dx = (gcx - ecx) / ew;
        const float dy = (gcy - ecy) / eh;
        const float dw = logf(gw / ew);
        const float dh = logf(gh / eh);

        const bool pos = lab > 0;

        float4 tg;
        tg.x = pos ? (dx - m0) * rs0 : 0.0f;
        tg.y = pos ? (dy - m1) * rs1 : 0.0f;
        tg.z = pos ? (dw - m2) * rs2 : 0.0f;
        tg.w = pos ? (dh - m3) * rs3 : 0.0f;

        float4 wi;
        wi.x = pos ? iw0 : 0.0f;
        wi.y = pos ? iw1 : 0.0f;
        wi.z = pos ? iw2 : 0.0f;
        wi.w = pos ? iw3 : 0.0f;

        float4 wo;
        wo.x = (wi.x > 0.0f) ? 1.0f : 0.0f;
        wo.y = (wi.y > 0.0f) ? 1.0f : 0.0f;
        wo.z = (wi.z > 0.0f) ? 1.0f : 0.0f;
        wo.w = (wi.w > 0.0f) ? 1.0f : 0.0f;

        out_t[i]  = tg;
        out_wi[i] = wi;
        out_wo[i] = wo;
    }
}

extern "C" void kernel_launch(void* const* d_in, const int* in_sizes, int n_in,
                              void* d_out, int out_size, void* d_ws, size_t ws_size,
                              hipStream_t stream)
{
    const float* gt_rois  = (const float*)d_in[0];
    const float* rois     = (const float*)d_in[1];
    const int*   labels   = (const int*)d_in[2];
    const float* means    = (const float*)d_in[3];
    const float* stds     = (const float*)d_in[4];
    const float* inside_w = (const float*)d_in[5];
    float* out = (float*)d_out;

    const int n = in_sizes[2];  // labels element count == N

    const int grid = (n + TILE - 1) / TILE;
    rcnn_target_kernel<<<grid, BLOCK, 0, stream>>>(
        gt_rois, rois, labels, means, stds, inside_w, out, n);
}

// Round 5
// 32.297 us; speedup vs baseline: 1.0153x; 1.0153x over previous
//
#include <hip/hip_runtime.h>
#include <hip/hip_bf16.h>

// RCNN bbox target generator: elementwise over N boxes. Memory-bound.
//
// R3 insight (rocprof): FETCH_SIZE=44MB << 88MB of inputs -> inputs are
// partially L3-resident across replays, but the 96MB of output stores
// allocate into L2/L3 and evict them. Fix: nontemporal (evict-first) output
// stores so the input set stays cached; steady-state HBM traffic -> ~96MB
// writes + small read residue.
//
// R4: fix compile error — __builtin_nontemporal_store needs a NATIVE vector
// type (ext_vector_type), not HIP_vector_type<float,4>.
//
// Output d_out (f32, 12N floats):
//   [0,4N) bbox_targets | [4N,8N) inside_weights | [8N,12N) outside_weights

#define BLOCK 256
#define TILE  512   // boxes per block (2 per thread)

typedef float f32x4 __attribute__((ext_vector_type(4)));

__global__ __launch_bounds__(BLOCK) void rcnn_target_kernel(
    const float* __restrict__ gt_rois,
    const float* __restrict__ rois,
    const int*   __restrict__ labels,
    const float* __restrict__ means,
    const float* __restrict__ stds,
    const float* __restrict__ inside_w,
    float* __restrict__ out,
    int n)
{
    __shared__ float sg[TILE * 5];   // 10240 B
    __shared__ float sr[TILE * 5];   // 10240 B

    const int t    = threadIdx.x;
    const int base = blockIdx.x * TILE;
    const int rem  = min(TILE, n - base);        // boxes in this tile
    const int nflt = 5 * rem;
    const int nvec = nflt >> 2;                  // whole float4s to stage

    const int i0 = base + t;
    const int i1 = base + BLOCK + t;

    // Issue label loads early so they overlap the staging loads.
    int lab0 = (t < rem)          ? labels[i0] : 0;
    int lab1 = (BLOCK + t < rem)  ? labels[i1] : 0;

    const f32x4* __restrict__ g4 = reinterpret_cast<const f32x4*>(gt_rois + (size_t)base * 5);
    const f32x4* __restrict__ r4 = reinterpret_cast<const f32x4*>(rois    + (size_t)base * 5);
    f32x4* __restrict__ sg4 = reinterpret_cast<f32x4*>(sg);
    f32x4* __restrict__ sr4 = reinterpret_cast<f32x4*>(sr);

    for (int idx = t; idx < nvec; idx += BLOCK) {
        sg4[idx] = g4[idx];
        sr4[idx] = r4[idx];
    }
    if (t == 0) {                                // scalar tail (partial last tile only)
        for (int f = nvec * 4; f < nflt; ++f) {
            sg[f] = gt_rois[(size_t)base * 5 + f];
            sr[f] = rois[(size_t)base * 5 + f];
        }
    }
    __syncthreads();

    // Parameter vectors: broadcast scalar loads, L1-resident.
    const float m0 = means[0], m1 = means[1], m2 = means[2], m3 = means[3];
    const float rs0 = 1.0f / stds[0], rs1 = 1.0f / stds[1];
    const float rs2 = 1.0f / stds[2], rs3 = 1.0f / stds[3];
    const float iw0 = inside_w[0], iw1 = inside_w[1];
    const float iw2 = inside_w[2], iw3 = inside_w[3];

    f32x4* __restrict__ out_t  = reinterpret_cast<f32x4*>(out);
    f32x4* __restrict__ out_wi = reinterpret_cast<f32x4*>(out + 4ull * (size_t)n);
    f32x4* __restrict__ out_wo = reinterpret_cast<f32x4*>(out + 8ull * (size_t)n);

    #pragma unroll
    for (int k = 0; k < 2; ++k) {
        const int lt = k * BLOCK + t;            // index within tile
        const int i  = base + lt;                // global box index
        if (i >= n) break;
        const int lab = (k == 0) ? lab0 : lab1;

        const float* g = sg + 5 * lt;            // gt box: record cols 0:4
        const float* r = sr + 5 * lt + 1;        // ex box: record cols 1:5

        const float gx1 = g[0], gy1 = g[1], gx2 = g[2], gy2 = g[3];
        const float ex1 = r[0], ey1 = r[1], ex2 = r[2], ey2 = r[3];

        const float ew  = ex2 - ex1 + 1.0f;
        const float eh  = ey2 - ey1 + 1.0f;
        const float ecx = ex1 + 0.5f * ew;
        const float ecy = ey1 + 0.5f * eh;
        const float gw  = gx2 - gx1 + 1.0f;
        const float gh  = gy2 - gy1 + 1.0f;
        const float gcx = gx1 + 0.5f * gw;
        const float gcy = gy1 + 0.5f * gh;

        const float dx = (gcx - ecx) / ew;
        const float dy = (gcy - ecy) / eh;
        const float dw = logf(gw / ew);
        const float dh = logf(gh / eh);

        const bool pos = lab > 0;

        f32x4 tg;
        tg.x = pos ? (dx - m0) * rs0 : 0.0f;
        tg.y = pos ? (dy - m1) * rs1 : 0.0f;
        tg.z = pos ? (dw - m2) * rs2 : 0.0f;
        tg.w = pos ? (dh - m3) * rs3 : 0.0f;

        f32x4 wi;
        wi.x = pos ? iw0 : 0.0f;
        wi.y = pos ? iw1 : 0.0f;
        wi.z = pos ? iw2 : 0.0f;
        wi.w = pos ? iw3 : 0.0f;

        f32x4 wo;
        wo.x = (wi.x > 0.0f) ? 1.0f : 0.0f;
        wo.y = (wi.y > 0.0f) ? 1.0f : 0.0f;
        wo.z = (wi.z > 0.0f) ? 1.0f : 0.0f;
        wo.w = (wi.w > 0.0f) ? 1.0f : 0.0f;

        // Nontemporal (evict-first) stores: outputs are never re-read by the
        // kernel; keep them from evicting the L3-resident input set.
        __builtin_nontemporal_store(tg, &out_t[i]);
        __builtin_nontemporal_store(wi, &out_wi[i]);
        __builtin_nontemporal_store(wo, &out_wo[i]);
    }
}

extern "C" void kernel_launch(void* const* d_in, const int* in_sizes, int n_in,
                              void* d_out, int out_size, void* d_ws, size_t ws_size,
                              hipStream_t stream)
{
    const float* gt_rois  = (const float*)d_in[0];
    const float* rois     = (const float*)d_in[1];
    const int*   labels   = (const int*)d_in[2];
    const float* means    = (const float*)d_in[3];
    const float* stds     = (const float*)d_in[4];
    const float* inside_w = (const float*)d_in[5];
    float* out = (float*)d_out;

    const int n = in_sizes[2];  // labels element count == N

    const int grid = (n + TILE - 1) / TILE;
    rcnn_target_kernel<<<grid, BLOCK, 0, stream>>>(
        gt_rois, rois, labels, means, stds, inside_w, out, n);
}